// Round 2
// baseline (370.491 us; speedup 1.0000x reference)
//
#include <hip/hip_runtime.h>
#include <stdint.h>

#define NTAG    10
#define SEQ     512
#define BATCH   8192
#define NEG_INF -10000.0f
#define BT10    (BATCH * NTAG)   // 81920: per-timestep dword stride

static __device__ __forceinline__ uint32_t umin32(uint32_t a, uint32_t b) {
    return a < b ? a : b;
}

// ---------------------------------------------------------------------------
// 16-way Viterbi reduce, VALU-only. fv values are exchanged across the 16-lane
// DPP row via row_ror (no LDS pipe, no lgkmcnt). tra[r] pairs the rotated
// value with the right transition (pidx[] was built by rotating nx itself, so
// the pairing is correct regardless of the HW rotate direction convention).
// vstar = exact max (binary fmaxf tree == jnp.max bitwise).
// bp    = min tag among candidates bitwise-equal to vstar == jnp.argmax
//         first-max tie semantics. Recovery is off the fv critical chain.
// ---------------------------------------------------------------------------
__device__ __forceinline__ void vit16(float fv, const float tra[16],
                                      const int pidx[16],
                                      float& vstar, uint32_t& bp)
{
    const int fvi = __float_as_int(fv);
    float c[16];
    c[0]  = fv + tra[0];
    c[1]  = __int_as_float(__builtin_amdgcn_mov_dpp(fvi, 0x121, 0xF, 0xF, false)) + tra[1];
    c[2]  = __int_as_float(__builtin_amdgcn_mov_dpp(fvi, 0x122, 0xF, 0xF, false)) + tra[2];
    c[3]  = __int_as_float(__builtin_amdgcn_mov_dpp(fvi, 0x123, 0xF, 0xF, false)) + tra[3];
    c[4]  = __int_as_float(__builtin_amdgcn_mov_dpp(fvi, 0x124, 0xF, 0xF, false)) + tra[4];
    c[5]  = __int_as_float(__builtin_amdgcn_mov_dpp(fvi, 0x125, 0xF, 0xF, false)) + tra[5];
    c[6]  = __int_as_float(__builtin_amdgcn_mov_dpp(fvi, 0x126, 0xF, 0xF, false)) + tra[6];
    c[7]  = __int_as_float(__builtin_amdgcn_mov_dpp(fvi, 0x127, 0xF, 0xF, false)) + tra[7];
    c[8]  = __int_as_float(__builtin_amdgcn_mov_dpp(fvi, 0x128, 0xF, 0xF, false)) + tra[8];
    c[9]  = __int_as_float(__builtin_amdgcn_mov_dpp(fvi, 0x129, 0xF, 0xF, false)) + tra[9];
    c[10] = __int_as_float(__builtin_amdgcn_mov_dpp(fvi, 0x12A, 0xF, 0xF, false)) + tra[10];
    c[11] = __int_as_float(__builtin_amdgcn_mov_dpp(fvi, 0x12B, 0xF, 0xF, false)) + tra[11];
    c[12] = __int_as_float(__builtin_amdgcn_mov_dpp(fvi, 0x12C, 0xF, 0xF, false)) + tra[12];
    c[13] = __int_as_float(__builtin_amdgcn_mov_dpp(fvi, 0x12D, 0xF, 0xF, false)) + tra[13];
    c[14] = __int_as_float(__builtin_amdgcn_mov_dpp(fvi, 0x12E, 0xF, 0xF, false)) + tra[14];
    c[15] = __int_as_float(__builtin_amdgcn_mov_dpp(fvi, 0x12F, 0xF, 0xF, false)) + tra[15];

    // exact max, binary tree (associative & exact for fp32 max, no NaNs)
    const float m01 = fmaxf(c[0], c[1]),  m23 = fmaxf(c[2], c[3]);
    const float m45 = fmaxf(c[4], c[5]),  m67 = fmaxf(c[6], c[7]);
    const float m89 = fmaxf(c[8], c[9]),  mAB = fmaxf(c[10], c[11]);
    const float mCD = fmaxf(c[12], c[13]), mEF = fmaxf(c[14], c[15]);
    const float m03 = fmaxf(m01, m23), m47 = fmaxf(m45, m67);
    const float m8B = fmaxf(m89, mAB), mCF = fmaxf(mCD, mEF);
    vstar = fmaxf(fmaxf(m03, m47), fmaxf(m8B, mCF));

    // first-max index: min tag among exact matches (pads can never match —
    // their candidates sit ~1e4 below every real candidate)
    uint32_t s[16];
#pragma unroll
    for (int r = 0; r < 16; ++r)
        s[r] = (c[r] == vstar) ? (uint32_t)pidx[r] : 31u;
    const uint32_t n01 = umin32(s[0], s[1]),   n23 = umin32(s[2], s[3]);
    const uint32_t n45 = umin32(s[4], s[5]),   n67 = umin32(s[6], s[7]);
    const uint32_t n89 = umin32(s[8], s[9]),   nAB = umin32(s[10], s[11]);
    const uint32_t nCD = umin32(s[12], s[13]), nEF = umin32(s[14], s[15]);
    const uint32_t n03 = umin32(n01, n23), n47 = umin32(n45, n67);
    const uint32_t n8B = umin32(n89, nAB), nCF = umin32(nCD, nEF);
    bp = umin32(umin32(n03, n47), umin32(n8B, nCF));
}

// ---------------------------------------------------------------------------
// Forward Viterbi, VALU-only exchange. Lane layout: 16 lanes per batch
// (tags 0..9 real, 10..15 padded with NEG_INF transitions), 4 batches/wave,
// 16 batches/block, 512 blocks -> 2048 waves = 2 waves/SIMD. No LDS, no DS
// ops, no barriers: the per-step serial chain is ~26 VALU cycles and the
// kernel is VALU issue-bound instead of DS-latency-bound.
// Padding safety: pad candidates = fv_pad + NEG_INF stay >= ~1e4 below every
// real candidate (fv_pad tracks max(fv) - 1e4), so they never win the max
// nor bitwise-match vstar. fp32 adds/max bitwise-identical to the reference.
// ---------------------------------------------------------------------------
__global__ __launch_bounds__(256, 2) void crf_fwd(
    const float* __restrict__ feats, const float* __restrict__ trans,
    float* __restrict__ path_score, int* __restrict__ last_tag,
    uint32_t* __restrict__ bpw)
{
    const int tid = threadIdx.x;
    const int nx  = tid & 15;                 // tag slot within 16-lane row
    const int row = tid >> 4;                 // 0..15 rows per block
    const int b   = blockIdx.x * 16 + row;    // exact: 512*16 = 8192
    const int nxc = (nx < NTAG) ? nx : (NTAG - 1);

    // source-tag per rotation, convention-proof: rotate the lane's own nx
    int pidx[16];
    pidx[0]  = nx;
    pidx[1]  = __builtin_amdgcn_mov_dpp(nx, 0x121, 0xF, 0xF, false);
    pidx[2]  = __builtin_amdgcn_mov_dpp(nx, 0x122, 0xF, 0xF, false);
    pidx[3]  = __builtin_amdgcn_mov_dpp(nx, 0x123, 0xF, 0xF, false);
    pidx[4]  = __builtin_amdgcn_mov_dpp(nx, 0x124, 0xF, 0xF, false);
    pidx[5]  = __builtin_amdgcn_mov_dpp(nx, 0x125, 0xF, 0xF, false);
    pidx[6]  = __builtin_amdgcn_mov_dpp(nx, 0x126, 0xF, 0xF, false);
    pidx[7]  = __builtin_amdgcn_mov_dpp(nx, 0x127, 0xF, 0xF, false);
    pidx[8]  = __builtin_amdgcn_mov_dpp(nx, 0x128, 0xF, 0xF, false);
    pidx[9]  = __builtin_amdgcn_mov_dpp(nx, 0x129, 0xF, 0xF, false);
    pidx[10] = __builtin_amdgcn_mov_dpp(nx, 0x12A, 0xF, 0xF, false);
    pidx[11] = __builtin_amdgcn_mov_dpp(nx, 0x12B, 0xF, 0xF, false);
    pidx[12] = __builtin_amdgcn_mov_dpp(nx, 0x12C, 0xF, 0xF, false);
    pidx[13] = __builtin_amdgcn_mov_dpp(nx, 0x12D, 0xF, 0xF, false);
    pidx[14] = __builtin_amdgcn_mov_dpp(nx, 0x12E, 0xF, 0xF, false);
    pidx[15] = __builtin_amdgcn_mov_dpp(nx, 0x12F, 0xF, 0xF, false);

    // transition addend per rotation: T[nx][pidx[r]], NEG_INF for pad lanes
    float trr[16];
#pragma unroll
    for (int r = 0; r < 16; ++r) {
        const int pp = pidx[r];
        trr[r] = (nx < NTAG && pp < NTAG) ? trans[nx * NTAG + pp] : NEG_INF;
    }

    float fv = (nx == 8) ? 0.0f : NEG_INF;    // START=0, else -1e4 (pads -1e4)

    const float* fp = feats + b * NTAG + nxc; // pad lanes read tag 9 (unused-safe)
    uint32_t* bp_out = bpw + b * NTAG + nx;   // only dereferenced when nx < 10

    // software pipeline: 8 feats (one bp-word period) prefetched ahead
    float fc[8];
#pragma unroll
    for (int j = 0; j < 8; ++j) fc[j] = fp[j * BT10];
    fp += 8 * BT10;

    for (int w = 0; w < SEQ / 8; ++w) {
        float fn[8];
        if (w < SEQ / 8 - 1) {
#pragma unroll
            for (int j = 0; j < 8; ++j) fn[j] = fp[j * BT10];
            fp += 8 * BT10;
        } else {
#pragma unroll
            for (int j = 0; j < 8; ++j) fn[j] = 0.0f;
        }

        uint32_t bacc = 0;
#pragma unroll
        for (int j = 0; j < 8; ++j) {
            float vstar; uint32_t bp;
            vit16(fv, trr, pidx, vstar, bp);
            fv = vstar + fc[j];               // exact same add as reference
            bacc |= bp << (4 * j);
        }
        if (nx < NTAG) bp_out[0] = bacc;
        bp_out += BT10;
#pragma unroll
        for (int j = 0; j < 8; ++j) fc[j] = fn[j];
    }

    // terminal: term[p] = fv[p] + T[STOP][p]; exact first-max across tags
    float ttr[16];
#pragma unroll
    for (int r = 0; r < 16; ++r) {
        const int pp = pidx[r];
        ttr[r] = (pp < NTAG) ? trans[9 * NTAG + pp] : NEG_INF;
    }
    {
        float vstar; uint32_t bt;
        vit16(fv, ttr, pidx, vstar, bt);
        if (nx == 0) { path_score[b] = vstar; last_tag[b] = (int)bt; }
    }
}

// ---------------------------------------------------------------------------
// Pass A: per (chunk c, batch b) compose the 32 per-step backpointer maps in
// registers. Loads coalesced (40 contiguous B/thread) and tag-independent.
// ---------------------------------------------------------------------------
__global__ __launch_bounds__(256) void crf_chunkmap(
    const uint32_t* __restrict__ bpw, uint64_t* __restrict__ cmap)
{
    const int tid = blockIdx.x * 256 + threadIdx.x;   // 131072 = 16 * 8192
    const int b = tid & (BATCH - 1);
    const int c = tid >> 13;

    uint32_t comp[NTAG];
#pragma unroll
    for (int t = 0; t < NTAG; ++t) comp[t] = t;       // identity

    for (int w = 3; w >= 0; --w) {                    // global word c*4+w
        const uint32_t* wp = bpw + (c * 4 + w) * BT10 + b * NTAG;
        const uint64_t q0 = *(const uint64_t*)(wp + 0);
        const uint64_t q1 = *(const uint64_t*)(wp + 2);
        const uint64_t q2 = *(const uint64_t*)(wp + 4);
        const uint64_t q3 = *(const uint64_t*)(wp + 6);
        const uint64_t q4 = *(const uint64_t*)(wp + 8);
        uint32_t wd[10];
        wd[0] = (uint32_t)q0; wd[1] = (uint32_t)(q0 >> 32);
        wd[2] = (uint32_t)q1; wd[3] = (uint32_t)(q1 >> 32);
        wd[4] = (uint32_t)q2; wd[5] = (uint32_t)(q2 >> 32);
        wd[6] = (uint32_t)q3; wd[7] = (uint32_t)(q3 >> 32);
        wd[8] = (uint32_t)q4; wd[9] = (uint32_t)(q4 >> 32);
#pragma unroll
        for (int t = 7; t >= 0; --t) {
            uint32_t lo = 0;
#pragma unroll
            for (int gg = 0; gg < 8; ++gg) lo |= ((wd[gg] >> (4 * t)) & 15u) << (4 * gg);
            const uint32_t hi = ((wd[8] >> (4 * t)) & 15u)
                              | (((wd[9] >> (4 * t)) & 15u) << 4);
            const uint64_t m = ((uint64_t)hi << 32) | lo;
#pragma unroll
            for (int q = 0; q < NTAG; ++q)
                comp[q] = (uint32_t)((m >> (comp[q] * 4)) & 15u);
        }
    }
    uint64_t out = 0;
#pragma unroll
    for (int q = 0; q < NTAG; ++q) out |= (uint64_t)comp[q] << (4 * q);
    cmap[tid] = out;                                   // tid = c*8192 + b
}

// ---------------------------------------------------------------------------
// Pass B: resolve chunk-entry tags (16 independent loads + register chain).
// ---------------------------------------------------------------------------
__global__ __launch_bounds__(256) void crf_resolve(
    const uint64_t* __restrict__ cmap, const int* __restrict__ last_tag,
    uint8_t* __restrict__ ebuf)
{
    const int b = blockIdx.x * 256 + threadIdx.x;      // 0..8191
    uint64_t cm[16];
#pragma unroll
    for (int c = 0; c < 16; ++c) cm[c] = cmap[c * BATCH + b];
    uint32_t tag = (uint32_t)last_tag[b];
    ebuf[15 * BATCH + b] = (uint8_t)tag;
#pragma unroll
    for (int c = 15; c >= 1; --c) {
        tag = (uint32_t)((cm[c] >> (tag * 4)) & 15u);
        ebuf[(c - 1) * BATCH + b] = (uint8_t)tag;
    }
}

// ---------------------------------------------------------------------------
// Pass C: emit. Re-walk each chunk with the known entry tag; word select by
// tag = cndmask tree (register-space); stores coalesced over b.
// ---------------------------------------------------------------------------
__global__ __launch_bounds__(256) void crf_emit(
    const uint32_t* __restrict__ bpw, const uint8_t* __restrict__ ebuf,
    float* __restrict__ best_path)
{
    const int tid = blockIdx.x * 256 + threadIdx.x;    // 131072
    const int b = tid & (BATCH - 1);
    const int c = tid >> 13;
    uint32_t tag = ebuf[c * BATCH + b];

    for (int w = 3; w >= 0; --w) {
        const uint32_t* wp = bpw + (c * 4 + w) * BT10 + b * NTAG;
        const uint64_t q0 = *(const uint64_t*)(wp + 0);
        const uint64_t q1 = *(const uint64_t*)(wp + 2);
        const uint64_t q2 = *(const uint64_t*)(wp + 4);
        const uint64_t q3 = *(const uint64_t*)(wp + 6);
        const uint64_t q4 = *(const uint64_t*)(wp + 8);
        uint32_t wd[10];
        wd[0] = (uint32_t)q0; wd[1] = (uint32_t)(q0 >> 32);
        wd[2] = (uint32_t)q1; wd[3] = (uint32_t)(q1 >> 32);
        wd[4] = (uint32_t)q2; wd[5] = (uint32_t)(q2 >> 32);
        wd[6] = (uint32_t)q3; wd[7] = (uint32_t)(q3 >> 32);
        wd[8] = (uint32_t)q4; wd[9] = (uint32_t)(q4 >> 32);
#pragma unroll
        for (int t = 7; t >= 0; --t) {
            best_path[(c * 32 + w * 8 + t) * BATCH + b] = (float)tag;  // tag_t
            const uint32_t s0 = (tag & 1) ? wd[1] : wd[0];
            const uint32_t s2 = (tag & 1) ? wd[3] : wd[2];
            const uint32_t s4 = (tag & 1) ? wd[5] : wd[4];
            const uint32_t s6 = (tag & 1) ? wd[7] : wd[6];
            const uint32_t s8 = (tag & 1) ? wd[9] : wd[8];
            const uint32_t t0 = (tag & 2) ? s2 : s0;
            const uint32_t t4 = (tag & 2) ? s6 : s4;
            const uint32_t u0 = (tag & 4) ? t4 : t0;
            const uint32_t sel = (tag & 8) ? s8 : u0;
            tag = (sel >> (4 * t)) & 15u;                              // tag_{t-1}
        }
    }
}

// ---------------------------------------------------------------------------
// d_ws layout (22.2 MB total):
//   [0, 20971520)            bpw  : 64 words x 81920 uint32 (nibble bp)
//   [20971520, +32768)       ltag : 8192 int32
//   [21004288, +1048576)     cmap : 16 x 8192 uint64 (packed chunk maps)
//   [22052864, +131072)      ebuf : 16 x 8192 bytes
// ---------------------------------------------------------------------------
extern "C" void kernel_launch(void* const* d_in, const int* in_sizes, int n_in,
                              void* d_out, int out_size, void* d_ws, size_t ws_size,
                              hipStream_t stream)
{
    const float* feats = (const float*)d_in[0];
    const float* trans = (const float*)d_in[1];

    float* out_f      = (float*)d_out;
    float* path_score = out_f;           // [8192]
    float* best_path  = out_f + BATCH;   // [512 * 8192]

    char* ws = (char*)d_ws;
    uint32_t* bpw  = (uint32_t*)ws;
    int*      ltag = (int*)(ws + 20971520);
    uint64_t* cmap = (uint64_t*)(ws + 21004288);
    uint8_t*  ebuf = (uint8_t*)(ws + 22052864);

    crf_fwd<<<512, 256, 0, stream>>>(feats, trans, path_score, ltag, bpw);
    crf_chunkmap<<<512, 256, 0, stream>>>(bpw, cmap);
    crf_resolve<<<32, 256, 0, stream>>>(cmap, ltag, ebuf);
    crf_emit<<<512, 256, 0, stream>>>(bpw, ebuf, best_path);
}